// Round 1
// 556.958 us; speedup vs baseline: 1.0011x; 1.0011x over previous
//
#include <hip/hip_runtime.h>

// GroupedQueryAttention: B=1, S=2048, D_IN=D_OUT=4096, NH=32, NKV=8, HD=128, causal.
// Pipeline: cast->bf16, fused QKV GEMM (256^2 8-phase MFMA), RoPE, V-transpose,
// flash attention, out GEMM.

typedef __bf16 bf16;
typedef __bf16 bf16x4 __attribute__((ext_vector_type(4)));
typedef __bf16 bf16x8 __attribute__((ext_vector_type(8)));
typedef float  f32x4  __attribute__((ext_vector_type(4)));

#define S_LEN   2048
#define DMODEL  4096
#define QKV_N   6144      // 4096 Q + 1024 K + 1024 V
#define K_OFF   4096
#define V_OFF   5120
#define HD      128
#define ATT_SCALE 0.08838834764831845f  // 1/sqrt(128)

// async global->LDS, 16B per lane; LDS dest is wave-uniform base + lane*16
__device__ __forceinline__ void gload16(const bf16* g, bf16* l) {
    __builtin_amdgcn_global_load_lds(
        (__attribute__((address_space(1))) void*)(g),
        (__attribute__((address_space(3))) void*)(l),
        16, 0, 0);
}

// ---------------- cast fp32 -> bf16, float4 vectorized ----------------
__global__ __launch_bounds__(256) void cast_f32_bf16(const float* __restrict__ in,
                                                     bf16* __restrict__ out, int n4) {
    int i = blockIdx.x * 256 + threadIdx.x;
    if (i >= n4) return;
    float4 v = reinterpret_cast<const float4*>(in)[i];
    bf16x4 o;
    o[0] = (bf16)v.x; o[1] = (bf16)v.y; o[2] = (bf16)v.z; o[3] = (bf16)v.w;
    reinterpret_cast<bf16x4*>(out)[i] = o;
}

// ================= GEMM: 256x256 tile, BK=64, 8-phase counted-vmcnt ===========
// C[M,N] = A[M,K] * B[N,K]^T (row-major, K contiguous). M,N multiples of 256,
// K multiple of 64. 512 threads = 8 waves (2M x 4N), wave computes 128x64.
//
// LDS (128 KiB): 2 slots x {A 256x64, B 256x64} bf16, double-buffered by K-tile.
// Chunk swizzle (T2, rule #21 both-sides): LDS 16B-chunk c of row r holds global
// chunk c ^ (r&7); staging pre-swizzles the GLOBAL source (LDS dest stays linear
// for global_load_lds), ds_read applies the same XOR.
//
// Staging schedule (1 half-tile = 128 rows x 64 cols = 2 gload16/thread):
//   phase0: A-half0(t+1)          -> other slot A      (dead since tile t-1 end)
//   phase1: A-half1(t+1), B-half0(t+2) -> cur slot B   (B consumed in phase0)
//   phase2: B-half1(t+2)
//   tile end: vmcnt(4)  -> completes through A1(t+1); B(t+2)'s 4 loads stay in
//   flight across the barrier (T4: never drain to 0 mid-loop).
template <typename OutT>
__global__ __launch_bounds__(512, 2) void gemm256(const bf16* __restrict__ A,
                                                  const bf16* __restrict__ B,
                                                  OutT* __restrict__ C,
                                                  int M, int N, int K, int ldc) {
    __shared__ bf16 Lsh[2 * 2 * 256 * 64];   // 128 KiB
    const int t    = threadIdx.x;
    const int lane = t & 63;
    const int wave = t >> 6;
    const int quad = lane >> 4, l15 = lane & 15;
    const int wm = wave >> 2, wn = wave & 3;

    // bijective XCD swizzle (m204): each XCD gets a contiguous wgid chunk
    int bid = blockIdx.y * gridDim.x + blockIdx.x;
    const int nwg = gridDim.x * gridDim.y;
    {
        const int q = nwg >> 3, r = nwg & 7;
        const int x = bid & 7, i = bid >> 3;
        bid = (x < r ? x * (q + 1) : r * (q + 1) + (x - r) * q) + i;
    }
    const int ntn = N >> 8;
    const int bm  = (bid / ntn) << 8;
    const int bn  = (bid % ntn) << 8;

    const bf16* Ablk = A + (size_t)bm * K;
    const bf16* Bblk = B + (size_t)bn * K;
    const int NT = K >> 6;

    bf16* L0A = Lsh;
    bf16* L0B = Lsh + 16384;
    bf16* L1A = Lsh + 32768;
    bf16* L1B = Lsh + 49152;

    // ---- staging helper inlined via lambda-free function ----
    // (declared as locals to keep addressing simple)
    // prologue: A(0),B(0) -> slot0 ; B(1) -> slot1 ; drain once (outside loop ok)
    {
        // stage_half expanded: j in {0,1}; r=j*64+(t>>3); src chunk=(t&7)^(r&7)
        #define STAGE_HALF(G, LR)                                              \
            {                                                                  \
                _Pragma("unroll")                                              \
                for (int j = 0; j < 2; ++j) {                                  \
                    const int r = j * 64 + (t >> 3);                           \
                    const int c = ((t & 7) ^ ((t >> 3) & 7)) << 3;             \
                    gload16((G) + (size_t)r * K + c,                           \
                            (LR) + j * 4096 + ((t >> 6) << 9));                \
                }                                                              \
            }
        STAGE_HALF(Ablk,                    L0A);
        STAGE_HALF(Ablk + (size_t)128 * K,  L0A + 8192);
        STAGE_HALF(Bblk,                    L0B);
        STAGE_HALF(Bblk + (size_t)128 * K,  L0B + 8192);
        if (NT > 1) {
            STAGE_HALF(Bblk + 64,                   L1B);
            STAGE_HALF(Bblk + (size_t)128 * K + 64, L1B + 8192);
        }
        asm volatile("s_waitcnt vmcnt(0)");
        __builtin_amdgcn_s_barrier();
    }

    f32x4 acc[8][4];
#pragma unroll
    for (int i = 0; i < 8; ++i)
#pragma unroll
        for (int j = 0; j < 4; ++j) acc[i][j] = (f32x4){0.f, 0.f, 0.f, 0.f};

    for (int tile = 0; tile < NT; ++tile) {
        bf16* As = (tile & 1) ? L1A : L0A;
        bf16* Bs = (tile & 1) ? L1B : L0B;
        bf16* An = (tile & 1) ? L0A : L1A;
        bf16x8 bfr[4][2];
#pragma unroll
        for (int q = 0; q < 4; ++q) {
            // ds-read this phase's A sub-tile (2 M-frags x 2 k-chunks)
            bf16x8 af[2][2];
#pragma unroll
            for (int dm = 0; dm < 2; ++dm)
#pragma unroll
                for (int kk = 0; kk < 2; ++kk) {
                    const int row = wm * 128 + q * 32 + dm * 16 + l15;
                    const int ch  = (kk * 4 + quad) ^ (row & 7);
                    af[dm][kk] = *reinterpret_cast<const bf16x8*>(
                        &As[row * 64 + (ch << 3)]);
                }
            if (q == 0) {
                // all B frags for this tile (held in regs across phases)
#pragma unroll
                for (int n = 0; n < 4; ++n)
#pragma unroll
                    for (int kk = 0; kk < 2; ++kk) {
                        const int row = wn * 64 + n * 16 + l15;
                        const int ch  = (kk * 4 + quad) ^ (row & 7);
                        bfr[n][kk] = *reinterpret_cast<const bf16x8*>(
                            &Bs[row * 64 + (ch << 3)]);
                    }
                if (tile + 1 < NT)
                    STAGE_HALF(Ablk + (size_t)(tile + 1) * 64, An);
            } else if (q == 1) {
                if (tile + 1 < NT)
                    STAGE_HALF(Ablk + (size_t)128 * K + (size_t)(tile + 1) * 64,
                               An + 8192);
                if (tile + 2 < NT)
                    STAGE_HALF(Bblk + (size_t)(tile + 2) * 64, Bs);
            } else if (q == 2) {
                if (tile + 2 < NT)
                    STAGE_HALF(Bblk + (size_t)128 * K + (size_t)(tile + 2) * 64,
                               Bs + 8192);
            }
            __builtin_amdgcn_s_barrier();
            asm volatile("s_waitcnt lgkmcnt(0)");
            __builtin_amdgcn_s_setprio(1);
#pragma unroll
            for (int dm = 0; dm < 2; ++dm)
#pragma unroll
                for (int n = 0; n < 4; ++n)
#pragma unroll
                    for (int kk = 0; kk < 2; ++kk)
                        acc[q * 2 + dm][n] = __builtin_amdgcn_mfma_f32_16x16x32_bf16(
                            af[dm][kk], bfr[n][kk], acc[q * 2 + dm][n], 0, 0, 0);
            __builtin_amdgcn_s_setprio(0);
            if (q < 3) {
                __builtin_amdgcn_s_barrier();
            } else {
                // tile boundary: complete through A1(t+1); keep B(t+2) in flight
                if (tile < NT - 2) { asm volatile("s_waitcnt vmcnt(4)"); }
                else               { asm volatile("s_waitcnt vmcnt(0)"); }
                __builtin_amdgcn_s_barrier();
            }
        }
    }
    #undef STAGE_HALF

    // epilogue: C/D layout col=l15, row=quad*4+r
#pragma unroll
    for (int mf = 0; mf < 8; ++mf) {
        const int row0 = bm + wm * 128 + mf * 16 + quad * 4;
#pragma unroll
        for (int nf = 0; nf < 4; ++nf) {
            const int col = bn + wn * 64 + nf * 16 + l15;
#pragma unroll
            for (int r = 0; r < 4; ++r)
                C[(size_t)(row0 + r) * ldc + col] = (OutT)acc[mf][nf][r];
        }
    }
}

// ---------------- RoPE on Q (32 heads) + K (8 heads) in the fused QKV buffer --------
__global__ __launch_bounds__(256) void rope_kernel(bf16* __restrict__ qkv,
                                                   const float* __restrict__ cosT,
                                                   const float* __restrict__ sinT) {
    const int col = blockIdx.x * 256 + threadIdx.x;  // 0 .. 40*64-1
    if (col >= 40 * 64) return;
    const int row  = blockIdx.y;
    const int head = col >> 6, d = col & 63;
    const size_t base = (size_t)row * QKV_N + head * 128 + d;
    const float x1 = (float)qkv[base];
    const float x2 = (float)qkv[base + 64];
    const float c  = cosT[row * 128 + d];
    const float s  = sinT[row * 128 + d];
    qkv[base]      = (bf16)(x1 * c - x2 * s);
    qkv[base + 64] = (bf16)(x2 * c + x1 * s);
}

// ---------------- V transpose: QKV V-region (2048 x 1024) -> Vt (1024 x 2048) -------
__global__ __launch_bounds__(256) void transpose_v(const bf16* __restrict__ qkv,
                                                   bf16* __restrict__ vt) {
    __shared__ bf16 T[64][72];
    const int c0 = blockIdx.x * 64;   // V column tile (0..1023)
    const int s0 = blockIdx.y * 64;   // sequence tile
    const int t  = threadIdx.x;
#pragma unroll
    for (int it = 0; it < 2; ++it) {
        const int sl = (t >> 3) + it * 32;
        const int c8 = (t & 7) * 8;
        bf16x8 v = *reinterpret_cast<const bf16x8*>(
            qkv + (size_t)(s0 + sl) * QKV_N + V_OFF + c0 + c8);
        *reinterpret_cast<bf16x8*>(&T[sl][c8]) = v;
    }
    __syncthreads();
#pragma unroll
    for (int it = 0; it < 2; ++it) {
        const int cl = (t >> 3) + it * 32;
        const int s8 = (t & 7) * 8;
        bf16x8 o;
#pragma unroll
        for (int e = 0; e < 8; ++e) o[e] = T[s8 + e][cl];
        *reinterpret_cast<bf16x8*>(vt + (size_t)(c0 + cl) * S_LEN + s0 + s8) = o;
    }
}

// ---------------- flash attention, causal, GQA group=4 ----------------
// 512 thr = 8 waves; BQ=128 (16 q-rows/wave), BKV=64, HD=128.
__global__ __launch_bounds__(512) void flash_attn(const bf16* __restrict__ qkv,
                                                  const bf16* __restrict__ vt,
                                                  bf16* __restrict__ ctx) {
    const int blk   = blockIdx.x;
    const int qtile = 15 - (blk >> 5);       // longest blocks dispatched first
    const int h     = blk & 31;
    const int kh    = h >> 2;
    const int q0    = qtile * 128;
    const int t     = threadIdx.x;
    const int wave  = t >> 6, lane = t & 63;
    const int quad  = lane >> 4, l15 = lane & 15;

    __shared__ bf16 Ks[64 * 128];    // 16 KB
    __shared__ bf16 Vs[128 * 64];    // 16 KB
    __shared__ bf16 Ps[8 * 16 * 72]; // 18 KB

    const bf16* Qb  = qkv + h * HD;
    const bf16* Kb  = qkv + K_OFF + kh * HD;
    const bf16* Vth = vt + (size_t)kh * HD * S_LEN;

    const int qrow_a = q0 + wave * 16 + l15;
    bf16x8 qf[4];
#pragma unroll
    for (int kk = 0; kk < 4; ++kk)
        qf[kk] = *reinterpret_cast<const bf16x8*>(
            Qb + (size_t)qrow_a * QKV_N + kk * 32 + quad * 8);

    float m_i[4], l_i[4];
    f32x4 o_acc[8];
#pragma unroll
    for (int r = 0; r < 4; ++r) { m_i[r] = -1e30f; l_i[r] = 0.f; }
#pragma unroll
    for (int dt = 0; dt < 8; ++dt) o_acc[dt] = (f32x4){0.f, 0.f, 0.f, 0.f};

    const int myrow = q0 + wave * 16 + quad * 4;
    bf16* PsW = Ps + wave * (16 * 72);

    for (int kv0 = 0; kv0 < q0 + 128; kv0 += 64) {
        __syncthreads();
#pragma unroll
        for (int it = 0; it < 2; ++it) {
            const int rb = wave * 8 + it * 4;
            const int r  = rb + (lane >> 4);
            const int cg = (lane & 15) ^ (r & 15);
            gload16(Kb + (size_t)(kv0 + r) * QKV_N + cg * 8, Ks + rb * 128);
        }
#pragma unroll
        for (int it = 0; it < 2; ++it) {
            const int db = wave * 16 + it * 8;
            const int d  = db + (lane >> 3);
            const int cg = (lane & 7) ^ (d & 7);
            gload16(Vth + (size_t)d * S_LEN + kv0 + cg * 8, Vs + db * 64);
        }
        __syncthreads();

        float sv[4][4];
        const bool need_mask = (kv0 + 63) > q0;  // block-uniform
#pragma unroll
        for (int j = 0; j < 4; ++j) {
            f32x4 s = (f32x4){0.f, 0.f, 0.f, 0.f};
#pragma unroll
            for (int kk = 0; kk < 4; ++kk) {
                const int cd = kk * 4 + quad;
                bf16x8 kf = *reinterpret_cast<const bf16x8*>(
                    &Ks[(j * 16 + l15) * 128 + ((cd ^ l15) & 15) * 8]);
                s = __builtin_amdgcn_mfma_f32_16x16x32_bf16(qf[kk], kf, s, 0, 0, 0);
            }
            if (need_mask) {
#pragma unroll
                for (int r = 0; r < 4; ++r)
                    sv[j][r] = ((kv0 + j * 16 + l15) <= (myrow + r))
                                   ? s[r] * ATT_SCALE : -1e30f;
            } else {
#pragma unroll
                for (int r = 0; r < 4; ++r) sv[j][r] = s[r] * ATT_SCALE;
            }
        }

        float al[4];
#pragma unroll
        for (int r = 0; r < 4; ++r) {
            float mt = fmaxf(fmaxf(sv[0][r], sv[1][r]), fmaxf(sv[2][r], sv[3][r]));
#pragma unroll
            for (int off = 1; off < 16; off <<= 1) mt = fmaxf(mt, __shfl_xor(mt, off));
            const float mn = fmaxf(m_i[r], mt);
            al[r] = __expf(m_i[r] - mn);
            m_i[r] = mn;
            float rs = 0.f;
#pragma unroll
            for (int j = 0; j < 4; ++j) {
                const float p = __expf(sv[j][r] - mn);
                rs += p;
                PsW[(quad * 4 + r) * 72 + j * 16 + l15] = (bf16)p;
            }
#pragma unroll
            for (int off = 1; off < 16; off <<= 1) rs += __shfl_xor(rs, off);
            l_i[r] = l_i[r] * al[r] + rs;
        }

#pragma unroll
        for (int dt = 0; dt < 8; ++dt) {
            o_acc[dt][0] *= al[0]; o_acc[dt][1] *= al[1];
            o_acc[dt][2] *= al[2]; o_acc[dt][3] *= al[3];
        }

        bf16x8 pa[2];
        pa[0] = *reinterpret_cast<const bf16x8*>(&PsW[l15 * 72 + quad * 8]);
        pa[1] = *reinterpret_cast<const bf16x8*>(&PsW[l15 * 72 + 32 + quad * 8]);
#pragma unroll
        for (int dt = 0; dt < 8; ++dt) {
#pragma unroll
            for (int c = 0; c < 2; ++c) {
                const int ck = c * 4 + quad;
                bf16x8 vb = *reinterpret_cast<const bf16x8*>(
                    &Vs[(dt * 16 + l15) * 64 + ((ck ^ (l15 & 7)) & 7) * 8]);
                o_acc[dt] = __builtin_amdgcn_mfma_f32_16x16x32_bf16(pa[c], vb, o_acc[dt], 0, 0, 0);
            }
        }
    }

#pragma unroll
    for (int dt = 0; dt < 8; ++dt)
#pragma unroll
        for (int r = 0; r < 4; ++r)
            ctx[(size_t)(myrow + r) * DMODEL + h * HD + dt * 16 + l15] =
                (bf16)(o_acc[dt][r] / l_i[r]);
}

// ---------------- launch ----------------
extern "C" void kernel_launch(void* const* d_in, const int* in_sizes, int n_in,
                              void* d_out, int out_size, void* d_ws, size_t ws_size,
                              hipStream_t stream) {
    const float* x    = (const float*)d_in[0];
    const float* cosT = (const float*)d_in[1];
    const float* sinT = (const float*)d_in[2];
    const float* Wq   = (const float*)d_in[3];
    const float* Wk   = (const float*)d_in[4];
    const float* Wv   = (const float*)d_in[5];
    const float* Wo   = (const float*)d_in[6];
    float* out = (float*)d_out;

    // workspace layout (bf16 elems): xb | Wqkv | Wo | QKV | ctx | Vt  (~147 MiB)
    bf16* xb   = (bf16*)d_ws;
    bf16* Wqkv = xb   + (size_t)S_LEN * DMODEL;        // 6144 x 4096
    bf16* Wob  = Wqkv + (size_t)QKV_N * DMODEL;        // 4096 x 4096
    bf16* QKV  = Wob  + (size_t)DMODEL * DMODEL;       // 2048 x 6144
    bf16* ctx  = QKV  + (size_t)S_LEN * QKV_N;         // 2048 x 4096
    bf16* Vt   = ctx  + (size_t)S_LEN * DMODEL;        // 1024 x 2048

    cast_f32_bf16<<<(S_LEN * DMODEL / 4 + 255) / 256, 256, 0, stream>>>(x, xb, S_LEN * DMODEL / 4);
    cast_f32_bf16<<<(DMODEL * DMODEL / 4 + 255) / 256, 256, 0, stream>>>(Wq, Wqkv, DMODEL * DMODEL / 4);
    cast_f32_bf16<<<(1024 * DMODEL / 4 + 255) / 256, 256, 0, stream>>>(
        Wk, Wqkv + (size_t)4096 * DMODEL, 1024 * DMODEL / 4);
    cast_f32_bf16<<<(1024 * DMODEL / 4 + 255) / 256, 256, 0, stream>>>(
        Wv, Wqkv + (size_t)5120 * DMODEL, 1024 * DMODEL / 4);
    cast_f32_bf16<<<(DMODEL * DMODEL / 4 + 255) / 256, 256, 0, stream>>>(Wo, Wob, DMODEL * DMODEL / 4);

    // fused QKV projection: (2048 x 4096) @ (6144 x 4096)^T -> 2048 x 6144 bf16
    gemm256<bf16><<<dim3(QKV_N / 256, S_LEN / 256), 512, 0, stream>>>(
        xb, Wqkv, QKV, S_LEN, QKV_N, DMODEL, QKV_N);

    // RoPE on Q (heads 0..31) and K (heads 32..39 of the packed buffer)
    rope_kernel<<<dim3(10, S_LEN), 256, 0, stream>>>(QKV, cosT, sinT);

    // V transpose for coalesced flash staging
    transpose_v<<<dim3(16, 32), 256, 0, stream>>>(QKV, Vt);

    // flash attention -> ctx bf16 (2048 x 4096); longest-first 1D grid
    flash_attn<<<dim3(16 * 32), 512, 0, stream>>>(QKV, Vt, ctx);

    // output projection: (2048 x 4096) @ (4096 x 4096)^T -> fp32 out
    gemm256<float><<<dim3(DMODEL / 256, S_LEN / 256), 512, 0, stream>>>(
        ctx, Wob, out, S_LEN, DMODEL, DMODEL, DMODEL);
}

// Round 5
// 554.662 us; speedup vs baseline: 1.0052x; 1.0041x over previous
//
#include <hip/hip_runtime.h>

// GroupedQueryAttention: B=1, S=2048, D_IN=D_OUT=4096, NH=32, NKV=8, HD=128, causal.
// Pipeline: cast->bf16, fused QKV GEMM (256^2 8-phase MFMA), RoPE, V-transpose,
// flash attention, out GEMM.

typedef __bf16 bf16;
typedef __bf16 bf16x4 __attribute__((ext_vector_type(4)));
typedef __bf16 bf16x8 __attribute__((ext_vector_type(8)));
typedef float  f32x4  __attribute__((ext_vector_type(4)));

#define S_LEN   2048
#define DMODEL  4096
#define QKV_N   6144      // 4096 Q + 1024 K + 1024 V
#define K_OFF   4096
#define V_OFF   5120
#define HD      128
#define ATT_SCALE 0.08838834764831845f  // 1/sqrt(128)

// async global->LDS, 16B per lane; LDS dest is wave-uniform base + lane*16
__device__ __forceinline__ void gload16(const bf16* g, bf16* l) {
    __builtin_amdgcn_global_load_lds(
        (__attribute__((address_space(1))) void*)(g),
        (__attribute__((address_space(3))) void*)(l),
        16, 0, 0);
}

// ---------------- cast fp32 -> bf16, float4 vectorized ----------------
__global__ __launch_bounds__(256) void cast_f32_bf16(const float* __restrict__ in,
                                                     bf16* __restrict__ out, int n4) {
    int i = blockIdx.x * 256 + threadIdx.x;
    if (i >= n4) return;
    float4 v = reinterpret_cast<const float4*>(in)[i];
    bf16x4 o;
    o[0] = (bf16)v.x; o[1] = (bf16)v.y; o[2] = (bf16)v.z; o[3] = (bf16)v.w;
    reinterpret_cast<bf16x4*>(out)[i] = o;
}

// ================= GEMM: 256x256 tile, BK=64, 8-phase counted-vmcnt ===========
// C[M,N] = A[M,K] * B[N,K]^T (row-major, K contiguous). M,N multiples of 256,
// K multiple of 64. 512 threads = 8 waves (2M x 4N), wave computes 128x64.
// bn-MAJOR bid ordering: consecutive bids share the (large) B panel -> same XCD
// L2 holds B; A (16 MB) is served by L3 across XCDs.
template <typename OutT>
__global__ __launch_bounds__(512, 2) void gemm256(const bf16* __restrict__ A,
                                                  const bf16* __restrict__ B,
                                                  OutT* __restrict__ C,
                                                  int M, int N, int K, int ldc) {
    __shared__ bf16 Lsh[2 * 2 * 256 * 64];   // 128 KiB
    const int t    = threadIdx.x;
    const int lane = t & 63;
    const int wave = t >> 6;
    const int quad = lane >> 4, l15 = lane & 15;
    const int wm = wave >> 2, wn = wave & 3;

    // bijective XCD swizzle (m204): each XCD gets a contiguous wgid chunk
    int bid = blockIdx.y * gridDim.x + blockIdx.x;
    const int nwg = gridDim.x * gridDim.y;
    {
        const int q = nwg >> 3, r = nwg & 7;
        const int x = bid & 7, i = bid >> 3;
        bid = (x < r ? x * (q + 1) : r * (q + 1) + (x - r) * q) + i;
    }
    const int ntm = M >> 8;
    const int bm  = (bid % ntm) << 8;   // bn-major: consecutive bids share bn
    const int bn  = (bid / ntm) << 8;

    const bf16* Ablk = A + (size_t)bm * K;
    const bf16* Bblk = B + (size_t)bn * K;
    const int NT = K >> 6;

    bf16* L0A = Lsh;
    bf16* L0B = Lsh + 16384;
    bf16* L1A = Lsh + 32768;
    bf16* L1B = Lsh + 49152;

    {
        #define STAGE_HALF(G, LR)                                              \
            {                                                                  \
                _Pragma("unroll")                                              \
                for (int j = 0; j < 2; ++j) {                                  \
                    const int r = j * 64 + (t >> 3);                           \
                    const int c = ((t & 7) ^ ((t >> 3) & 7)) << 3;             \
                    gload16((G) + (size_t)r * K + c,                           \
                            (LR) + j * 4096 + ((t >> 6) << 9));                \
                }                                                              \
            }
        STAGE_HALF(Ablk,                    L0A);
        STAGE_HALF(Ablk + (size_t)128 * K,  L0A + 8192);
        STAGE_HALF(Bblk,                    L0B);
        STAGE_HALF(Bblk + (size_t)128 * K,  L0B + 8192);
        if (NT > 1) {
            STAGE_HALF(Bblk + 64,                   L1B);
            STAGE_HALF(Bblk + (size_t)128 * K + 64, L1B + 8192);
        }
        asm volatile("s_waitcnt vmcnt(0)" ::: "memory");
        __builtin_amdgcn_s_barrier();
    }

    f32x4 acc[8][4];
#pragma unroll
    for (int i = 0; i < 8; ++i)
#pragma unroll
        for (int j = 0; j < 4; ++j) acc[i][j] = (f32x4){0.f, 0.f, 0.f, 0.f};

    for (int tile = 0; tile < NT; ++tile) {
        bf16* As = (tile & 1) ? L1A : L0A;
        bf16* Bs = (tile & 1) ? L1B : L0B;
        bf16* An = (tile & 1) ? L0A : L1A;
        bf16x8 bfr[4][2];
#pragma unroll
        for (int q = 0; q < 4; ++q) {
            bf16x8 af[2][2];
#pragma unroll
            for (int dm = 0; dm < 2; ++dm)
#pragma unroll
                for (int kk = 0; kk < 2; ++kk) {
                    const int row = wm * 128 + q * 32 + dm * 16 + l15;
                    const int ch  = (kk * 4 + quad) ^ (row & 7);
                    af[dm][kk] = *reinterpret_cast<const bf16x8*>(
                        &As[row * 64 + (ch << 3)]);
                }
            if (q == 0) {
#pragma unroll
                for (int n = 0; n < 4; ++n)
#pragma unroll
                    for (int kk = 0; kk < 2; ++kk) {
                        const int row = wn * 64 + n * 16 + l15;
                        const int ch  = (kk * 4 + quad) ^ (row & 7);
                        bfr[n][kk] = *reinterpret_cast<const bf16x8*>(
                            &Bs[row * 64 + (ch << 3)]);
                    }
                if (tile + 1 < NT)
                    STAGE_HALF(Ablk + (size_t)(tile + 1) * 64, An);
            } else if (q == 1) {
                if (tile + 1 < NT)
                    STAGE_HALF(Ablk + (size_t)128 * K + (size_t)(tile + 1) * 64,
                               An + 8192);
                if (tile + 2 < NT)
                    STAGE_HALF(Bblk + (size_t)(tile + 2) * 64, Bs);
            } else if (q == 2) {
                if (tile + 2 < NT)
                    STAGE_HALF(Bblk + (size_t)128 * K + (size_t)(tile + 2) * 64,
                               Bs + 8192);
            }
            __builtin_amdgcn_s_barrier();
            asm volatile("s_waitcnt lgkmcnt(0)" ::: "memory");
            __builtin_amdgcn_s_setprio(1);
#pragma unroll
            for (int dm = 0; dm < 2; ++dm)
#pragma unroll
                for (int n = 0; n < 4; ++n)
#pragma unroll
                    for (int kk = 0; kk < 2; ++kk)
                        acc[q * 2 + dm][n] = __builtin_amdgcn_mfma_f32_16x16x32_bf16(
                            af[dm][kk], bfr[n][kk], acc[q * 2 + dm][n], 0, 0, 0);
            __builtin_amdgcn_s_setprio(0);
            if (q < 3) {
                __builtin_amdgcn_s_barrier();
            } else {
                if (tile < NT - 2) { asm volatile("s_waitcnt vmcnt(4)" ::: "memory"); }
                else               { asm volatile("s_waitcnt vmcnt(0)" ::: "memory"); }
                __builtin_amdgcn_s_barrier();
            }
        }
    }
    #undef STAGE_HALF

#pragma unroll
    for (int mf = 0; mf < 8; ++mf) {
        const int row0 = bm + wm * 128 + mf * 16 + quad * 4;
#pragma unroll
        for (int nf = 0; nf < 4; ++nf) {
            const int col = bn + wn * 64 + nf * 16 + l15;
#pragma unroll
            for (int r = 0; r < 4; ++r)
                C[(size_t)(row0 + r) * ldc + col] = (OutT)acc[mf][nf][r];
        }
    }
}

// ---------------- RoPE on Q (32 heads) + K (8 heads) in the fused QKV buffer --------
__global__ __launch_bounds__(256) void rope_kernel(bf16* __restrict__ qkv,
                                                   const float* __restrict__ cosT,
                                                   const float* __restrict__ sinT) {
    const int col = blockIdx.x * 256 + threadIdx.x;  // 0 .. 40*64-1
    if (col >= 40 * 64) return;
    const int row  = blockIdx.y;
    const int head = col >> 6, d = col & 63;
    const size_t base = (size_t)row * QKV_N + head * 128 + d;
    const float x1 = (float)qkv[base];
    const float x2 = (float)qkv[base + 64];
    const float c  = cosT[row * 128 + d];
    const float s  = sinT[row * 128 + d];
    qkv[base]      = (bf16)(x1 * c - x2 * s);
    qkv[base + 64] = (bf16)(x2 * c + x1 * s);
}

// ---------------- V transpose: QKV V-region (2048 x 1024) -> Vt (1024 x 2048) -------
__global__ __launch_bounds__(256) void transpose_v(const bf16* __restrict__ qkv,
                                                   bf16* __restrict__ vt) {
    __shared__ bf16 T[64][72];
    const int c0 = blockIdx.x * 64;   // V column tile (0..1023)
    const int s0 = blockIdx.y * 64;   // sequence tile
    const int t  = threadIdx.x;
#pragma unroll
    for (int it = 0; it < 2; ++it) {
        const int sl = (t >> 3) + it * 32;
        const int c8 = (t & 7) * 8;
        bf16x8 v = *reinterpret_cast<const bf16x8*>(
            qkv + (size_t)(s0 + sl) * QKV_N + V_OFF + c0 + c8);
        *reinterpret_cast<bf16x8*>(&T[sl][c8]) = v;
    }
    __syncthreads();
#pragma unroll
    for (int it = 0; it < 2; ++it) {
        const int cl = (t >> 3) + it * 32;
        const int s8 = (t & 7) * 8;
        bf16x8 o;
#pragma unroll
        for (int e = 0; e < 8; ++e) o[e] = T[s8 + e][cl];
        *reinterpret_cast<bf16x8*>(vt + (size_t)(c0 + cl) * S_LEN + s0 + s8) = o;
    }
}

// ---------------- flash attention, causal, GQA group=4 (round-1 proven) ----------
// 512 thr = 8 waves; BQ=128 (16 q-rows/wave), BKV=64, HD=128.
__global__ __launch_bounds__(512) void flash_attn(const bf16* __restrict__ qkv,
                                                  const bf16* __restrict__ vt,
                                                  bf16* __restrict__ ctx) {
    const int blk   = blockIdx.x;
    const int qtile = 15 - (blk >> 5);       // longest blocks dispatched first
    const int h     = blk & 31;
    const int kh    = h >> 2;
    const int q0    = qtile * 128;
    const int t     = threadIdx.x;
    const int wave  = t >> 6, lane = t & 63;
    const int quad  = lane >> 4, l15 = lane & 15;

    __shared__ bf16 Ks[64 * 128];    // 16 KB
    __shared__ bf16 Vs[128 * 64];    // 16 KB
    __shared__ bf16 Ps[8 * 16 * 72]; // 18 KB

    const bf16* Qb  = qkv + h * HD;
    const bf16* Kb  = qkv + K_OFF + kh * HD;
    const bf16* Vth = vt + (size_t)kh * HD * S_LEN;

    const int qrow_a = q0 + wave * 16 + l15;
    bf16x8 qf[4];
#pragma unroll
    for (int kk = 0; kk < 4; ++kk)
        qf[kk] = *reinterpret_cast<const bf16x8*>(
            Qb + (size_t)qrow_a * QKV_N + kk * 32 + quad * 8);

    float m_i[4], l_i[4];
    f32x4 o_acc[8];
#pragma unroll
    for (int r = 0; r < 4; ++r) { m_i[r] = -1e30f; l_i[r] = 0.f; }
#pragma unroll
    for (int dt = 0; dt < 8; ++dt) o_acc[dt] = (f32x4){0.f, 0.f, 0.f, 0.f};

    const int myrow = q0 + wave * 16 + quad * 4;
    bf16* PsW = Ps + wave * (16 * 72);

    for (int kv0 = 0; kv0 < q0 + 128; kv0 += 64) {
        __syncthreads();
#pragma unroll
        for (int it = 0; it < 2; ++it) {
            const int rb = wave * 8 + it * 4;
            const int r  = rb + (lane >> 4);
            const int cg = (lane & 15) ^ (r & 15);
            gload16(Kb + (size_t)(kv0 + r) * QKV_N + cg * 8, Ks + rb * 128);
        }
#pragma unroll
        for (int it = 0; it < 2; ++it) {
            const int db = wave * 16 + it * 8;
            const int d  = db + (lane >> 3);
            const int cg = (lane & 7) ^ (d & 7);
            gload16(Vth + (size_t)d * S_LEN + kv0 + cg * 8, Vs + db * 64);
        }
        __syncthreads();

        float sv[4][4];
        const bool need_mask = (kv0 + 63) > q0;  // block-uniform
#pragma unroll
        for (int j = 0; j < 4; ++j) {
            f32x4 s = (f32x4){0.f, 0.f, 0.f, 0.f};
#pragma unroll
            for (int kk = 0; kk < 4; ++kk) {
                const int cd = kk * 4 + quad;
                bf16x8 kf = *reinterpret_cast<const bf16x8*>(
                    &Ks[(j * 16 + l15) * 128 + ((cd ^ l15) & 15) * 8]);
                s = __builtin_amdgcn_mfma_f32_16x16x32_bf16(qf[kk], kf, s, 0, 0, 0);
            }
            if (need_mask) {
#pragma unroll
                for (int r = 0; r < 4; ++r)
                    sv[j][r] = ((kv0 + j * 16 + l15) <= (myrow + r))
                                   ? s[r] * ATT_SCALE : -1e30f;
            } else {
#pragma unroll
                for (int r = 0; r < 4; ++r) sv[j][r] = s[r] * ATT_SCALE;
            }
        }

        float al[4];
#pragma unroll
        for (int r = 0; r < 4; ++r) {
            float mt = fmaxf(fmaxf(sv[0][r], sv[1][r]), fmaxf(sv[2][r], sv[3][r]));
#pragma unroll
            for (int off = 1; off < 16; off <<= 1) mt = fmaxf(mt, __shfl_xor(mt, off));
            const float mn = fmaxf(m_i[r], mt);
            al[r] = __expf(m_i[r] - mn);
            m_i[r] = mn;
            float rs = 0.f;
#pragma unroll
            for (int j = 0; j < 4; ++j) {
                const float p = __expf(sv[j][r] - mn);
                rs += p;
                PsW[(quad * 4 + r) * 72 + j * 16 + l15] = (bf16)p;
            }
#pragma unroll
            for (int off = 1; off < 16; off <<= 1) rs += __shfl_xor(rs, off);
            l_i[r] = l_i[r] * al[r] + rs;
        }

#pragma unroll
        for (int dt = 0; dt < 8; ++dt) {
            o_acc[dt][0] *= al[0]; o_acc[dt][1] *= al[1];
            o_acc[dt][2] *= al[2]; o_acc[dt][3] *= al[3];
        }

        bf16x8 pa[2];
        pa[0] = *reinterpret_cast<const bf16x8*>(&PsW[l15 * 72 + quad * 8]);
        pa[1] = *reinterpret_cast<const bf16x8*>(&PsW[l15 * 72 + 32 + quad * 8]);
#pragma unroll
        for (int dt = 0; dt < 8; ++dt) {
#pragma unroll
            for (int c = 0; c < 2; ++c) {
                const int ck = c * 4 + quad;
                bf16x8 vb = *reinterpret_cast<const bf16x8*>(
                    &Vs[(dt * 16 + l15) * 64 + ((ck ^ (l15 & 7)) & 7) * 8]);
                o_acc[dt] = __builtin_amdgcn_mfma_f32_16x16x32_bf16(pa[c], vb, o_acc[dt], 0, 0, 0);
            }
        }
    }

#pragma unroll
    for (int dt = 0; dt < 8; ++dt)
#pragma unroll
        for (int r = 0; r < 4; ++r)
            ctx[(size_t)(myrow + r) * DMODEL + h * HD + dt * 16 + l15] =
                (bf16)(o_acc[dt][r] / l_i[r]);
}

// ---------------- launch ----------------
extern "C" void kernel_launch(void* const* d_in, const int* in_sizes, int n_in,
                              void* d_out, int out_size, void* d_ws, size_t ws_size,
                              hipStream_t stream) {
    const float* x    = (const float*)d_in[0];
    const float* cosT = (const float*)d_in[1];
    const float* sinT = (const float*)d_in[2];
    const float* Wq   = (const float*)d_in[3];
    const float* Wk   = (const float*)d_in[4];
    const float* Wv   = (const float*)d_in[5];
    const float* Wo   = (const float*)d_in[6];
    float* out = (float*)d_out;

    // workspace layout (bf16 elems): xb | Wqkv | Wo | QKV | ctx | Vt  (~147 MiB)
    bf16* xb   = (bf16*)d_ws;
    bf16* Wqkv = xb   + (size_t)S_LEN * DMODEL;        // 6144 x 4096
    bf16* Wob  = Wqkv + (size_t)QKV_N * DMODEL;        // 4096 x 4096
    bf16* QKV  = Wob  + (size_t)DMODEL * DMODEL;       // 2048 x 6144
    bf16* ctx  = QKV  + (size_t)S_LEN * QKV_N;         // 2048 x 4096
    bf16* Vt   = ctx  + (size_t)S_LEN * DMODEL;        // 1024 x 2048

    cast_f32_bf16<<<(S_LEN * DMODEL / 4 + 255) / 256, 256, 0, stream>>>(x, xb, S_LEN * DMODEL / 4);
    cast_f32_bf16<<<(DMODEL * DMODEL / 4 + 255) / 256, 256, 0, stream>>>(Wq, Wqkv, DMODEL * DMODEL / 4);
    cast_f32_bf16<<<(1024 * DMODEL / 4 + 255) / 256, 256, 0, stream>>>(
        Wk, Wqkv + (size_t)4096 * DMODEL, 1024 * DMODEL / 4);
    cast_f32_bf16<<<(1024 * DMODEL / 4 + 255) / 256, 256, 0, stream>>>(
        Wv, Wqkv + (size_t)5120 * DMODEL, 1024 * DMODEL / 4);
    cast_f32_bf16<<<(DMODEL * DMODEL / 4 + 255) / 256, 256, 0, stream>>>(Wo, Wob, DMODEL * DMODEL / 4);

    // fused QKV projection: (2048 x 4096) @ (6144 x 4096)^T -> 2048 x 6144 bf16
    gemm256<bf16><<<dim3(QKV_N / 256, S_LEN / 256), 512, 0, stream>>>(
        xb, Wqkv, QKV, S_LEN, QKV_N, DMODEL, QKV_N);

    // RoPE on Q (heads 0..31) and K (heads 32..39 of the packed buffer)
    rope_kernel<<<dim3(10, S_LEN), 256, 0, stream>>>(QKV, cosT, sinT);

    // V transpose for coalesced flash staging
    transpose_v<<<dim3(16, 32), 256, 0, stream>>>(QKV, Vt);

    // flash attention -> ctx bf16 (2048 x 4096); longest-first 1D grid
    flash_attn<<<dim3(16 * 32), 512, 0, stream>>>(QKV, Vt, ctx);

    // output projection: (2048 x 4096) @ (4096 x 4096)^T -> fp32 out
    gemm256<float><<<dim3(DMODEL / 256, S_LEN / 256), 512, 0, stream>>>(
        ctx, Wob, out, S_LEN, DMODEL, DMODEL, DMODEL);
}

// Round 8
// 516.730 us; speedup vs baseline: 1.0790x; 1.0734x over previous
//
#include <hip/hip_runtime.h>

// GroupedQueryAttention: B=1, S=2048, D_IN=D_OUT=4096, NH=32, NKV=8, HD=128, causal.
// Pipeline: cast->bf16, QKV GEMM (256^2 8-phase MFMA), RoPE, V-transpose,
// flash attention, out GEMM (128x256 gemmT, exact 256-block fill).

typedef __bf16 bf16;
typedef __bf16 bf16x4 __attribute__((ext_vector_type(4)));
typedef __bf16 bf16x8 __attribute__((ext_vector_type(8)));
typedef float  f32x4  __attribute__((ext_vector_type(4)));

#define S_LEN   2048
#define DMODEL  4096
#define QKV_N   6144      // 4096 Q + 1024 K + 1024 V
#define K_OFF   4096
#define V_OFF   5120
#define HD      128
#define ATT_SCALE 0.08838834764831845f  // 1/sqrt(128)

// async global->LDS, 16B per lane; LDS dest is wave-uniform base + lane*16
__device__ __forceinline__ void gload16(const bf16* g, bf16* l) {
    __builtin_amdgcn_global_load_lds(
        (__attribute__((address_space(1))) void*)(g),
        (__attribute__((address_space(3))) void*)(l),
        16, 0, 0);
}

// ---------------- cast fp32 -> bf16, float4 vectorized ----------------
__global__ __launch_bounds__(256) void cast_f32_bf16(const float* __restrict__ in,
                                                     bf16* __restrict__ out, int n4) {
    int i = blockIdx.x * 256 + threadIdx.x;
    if (i >= n4) return;
    float4 v = reinterpret_cast<const float4*>(in)[i];
    bf16x4 o;
    o[0] = (bf16)v.x; o[1] = (bf16)v.y; o[2] = (bf16)v.z; o[3] = (bf16)v.w;
    reinterpret_cast<bf16x4*>(out)[i] = o;
}

// ================= GEMM: 256x256 tile, BK=64, 8-phase counted-vmcnt ===========
// (round-5 harness-verified, unchanged)
template <typename OutT>
__global__ __launch_bounds__(512, 2) void gemm256(const bf16* __restrict__ A,
                                                  const bf16* __restrict__ B,
                                                  OutT* __restrict__ C,
                                                  int M, int N, int K, int ldc) {
    __shared__ bf16 Lsh[2 * 2 * 256 * 64];   // 128 KiB
    const int t    = threadIdx.x;
    const int lane = t & 63;
    const int wave = t >> 6;
    const int quad = lane >> 4, l15 = lane & 15;
    const int wm = wave >> 2, wn = wave & 3;

    // bijective XCD swizzle (m204): each XCD gets a contiguous wgid chunk
    int bid = blockIdx.y * gridDim.x + blockIdx.x;
    const int nwg = gridDim.x * gridDim.y;
    {
        const int q = nwg >> 3, r = nwg & 7;
        const int x = bid & 7, i = bid >> 3;
        bid = (x < r ? x * (q + 1) : r * (q + 1) + (x - r) * q) + i;
    }
    const int ntm = M >> 8;
    const int bm  = (bid % ntm) << 8;   // bn-major: consecutive bids share bn
    const int bn  = (bid / ntm) << 8;

    const bf16* Ablk = A + (size_t)bm * K;
    const bf16* Bblk = B + (size_t)bn * K;
    const int NT = K >> 6;

    bf16* L0A = Lsh;
    bf16* L0B = Lsh + 16384;
    bf16* L1A = Lsh + 32768;
    bf16* L1B = Lsh + 49152;

    {
        #define STAGE_HALF(G, LR)                                              \
            {                                                                  \
                _Pragma("unroll")                                              \
                for (int j = 0; j < 2; ++j) {                                  \
                    const int r = j * 64 + (t >> 3);                           \
                    const int c = ((t & 7) ^ ((t >> 3) & 7)) << 3;             \
                    gload16((G) + (size_t)r * K + c,                           \
                            (LR) + j * 4096 + ((t >> 6) << 9));                \
                }                                                              \
            }
        STAGE_HALF(Ablk,                    L0A);
        STAGE_HALF(Ablk + (size_t)128 * K,  L0A + 8192);
        STAGE_HALF(Bblk,                    L0B);
        STAGE_HALF(Bblk + (size_t)128 * K,  L0B + 8192);
        if (NT > 1) {
            STAGE_HALF(Bblk + 64,                   L1B);
            STAGE_HALF(Bblk + (size_t)128 * K + 64, L1B + 8192);
        }
        asm volatile("s_waitcnt vmcnt(0)" ::: "memory");
        __builtin_amdgcn_s_barrier();
    }

    f32x4 acc[8][4];
#pragma unroll
    for (int i = 0; i < 8; ++i)
#pragma unroll
        for (int j = 0; j < 4; ++j) acc[i][j] = (f32x4){0.f, 0.f, 0.f, 0.f};

    for (int tile = 0; tile < NT; ++tile) {
        bf16* As = (tile & 1) ? L1A : L0A;
        bf16* Bs = (tile & 1) ? L1B : L0B;
        bf16* An = (tile & 1) ? L0A : L1A;
        bf16x8 bfr[4][2];
#pragma unroll
        for (int q = 0; q < 4; ++q) {
            bf16x8 af[2][2];
#pragma unroll
            for (int dm = 0; dm < 2; ++dm)
#pragma unroll
                for (int kk = 0; kk < 2; ++kk) {
                    const int row = wm * 128 + q * 32 + dm * 16 + l15;
                    const int ch  = (kk * 4 + quad) ^ (row & 7);
                    af[dm][kk] = *reinterpret_cast<const bf16x8*>(
                        &As[row * 64 + (ch << 3)]);
                }
            if (q == 0) {
#pragma unroll
                for (int n = 0; n < 4; ++n)
#pragma unroll
                    for (int kk = 0; kk < 2; ++kk) {
                        const int row = wn * 64 + n * 16 + l15;
                        const int ch  = (kk * 4 + quad) ^ (row & 7);
                        bfr[n][kk] = *reinterpret_cast<const bf16x8*>(
                            &Bs[row * 64 + (ch << 3)]);
                    }
                if (tile + 1 < NT)
                    STAGE_HALF(Ablk + (size_t)(tile + 1) * 64, An);
            } else if (q == 1) {
                if (tile + 1 < NT)
                    STAGE_HALF(Ablk + (size_t)128 * K + (size_t)(tile + 1) * 64,
                               An + 8192);
                if (tile + 2 < NT)
                    STAGE_HALF(Bblk + (size_t)(tile + 2) * 64, Bs);
            } else if (q == 2) {
                if (tile + 2 < NT)
                    STAGE_HALF(Bblk + (size_t)128 * K + (size_t)(tile + 2) * 64,
                               Bs + 8192);
            }
            __builtin_amdgcn_s_barrier();
            asm volatile("s_waitcnt lgkmcnt(0)" ::: "memory");
            __builtin_amdgcn_s_setprio(1);
#pragma unroll
            for (int dm = 0; dm < 2; ++dm)
#pragma unroll
                for (int n = 0; n < 4; ++n)
#pragma unroll
                    for (int kk = 0; kk < 2; ++kk)
                        acc[q * 2 + dm][n] = __builtin_amdgcn_mfma_f32_16x16x32_bf16(
                            af[dm][kk], bfr[n][kk], acc[q * 2 + dm][n], 0, 0, 0);
            __builtin_amdgcn_s_setprio(0);
            if (q < 3) {
                __builtin_amdgcn_s_barrier();
            } else {
                if (tile < NT - 2) { asm volatile("s_waitcnt vmcnt(4)" ::: "memory"); }
                else               { asm volatile("s_waitcnt vmcnt(0)" ::: "memory"); }
                __builtin_amdgcn_s_barrier();
            }
        }
    }
    #undef STAGE_HALF

#pragma unroll
    for (int mf = 0; mf < 8; ++mf) {
        const int row0 = bm + wm * 128 + mf * 16 + quad * 4;
#pragma unroll
        for (int nf = 0; nf < 4; ++nf) {
            const int col = bn + wn * 64 + nf * 16 + l15;
#pragma unroll
            for (int r = 0; r < 4; ++r)
                C[(size_t)(row0 + r) * ldc + col] = (OutT)acc[mf][nf][r];
        }
    }
}

// ================= gemmT: BM=MF*32 x BN=NF*64 tile, same 8-phase structure ====
// Used here ONLY as gemmT<float,4,4> (128x256) for the out-projection ->
// 16x16 = 256 blocks = exact CU fill (the old 256^2 launch was 128 blocks = 50%).
// Staging in 64-row units (1 gload16/thread/unit): nA=BM/64, nB=BN/64 spread
// over phases 0-2 (A(t+1) first, then B(t+2)). FIFO at tile end:
//   [B(t+1) nB][A(t+1) nA][B(t+2) nB] -> vmcnt(nB) completes the first two,
//   keeps B(t+2) in flight (never drain mid-loop).
template <typename OutT, int MF, int NF>
__global__ __launch_bounds__(512, 2) void gemmT(const bf16* __restrict__ A,
                                                const bf16* __restrict__ B,
                                                OutT* __restrict__ C,
                                                int M, int N, int K, int ldc) {
    constexpr int BM = MF * 32, BN = NF * 64;
    constexpr int nA = BM / 64, nB = BN / 64;
    constexpr int TU = nA + nB;           // stage units per tile
    constexpr int CEIL = (TU + 2) / 3;    // units per phase (phases 0..2)
    constexpr int AE = BM * 64, BE = BN * 64;
    constexpr int MPP = MF / 4;           // M-frags per phase (4 phases)

    __shared__ bf16 Lsh[2 * (AE + BE)];
    const int t    = threadIdx.x;
    const int lane = t & 63;
    const int quad = lane >> 4, l15 = lane & 15;
    const int wave = t >> 6;
    const int wm = wave >> 2, wn = wave & 3;

    // bijective XCD swizzle (m204)
    int bid = blockIdx.y * gridDim.x + blockIdx.x;
    const int nwg = gridDim.x * gridDim.y;
    {
        const int q = nwg >> 3, r = nwg & 7;
        const int x = bid & 7, i = bid >> 3;
        bid = (x < r ? x * (q + 1) : r * (q + 1) + (x - r) * q) + i;
    }
    const int ntm = M / BM;
    const int bm  = (bid % ntm) * BM;   // bn-major: consecutive bids share bn
    const int bn  = (bid / ntm) * BN;

    const bf16* Ablk = A + (size_t)bm * K;
    const bf16* Bblk = B + (size_t)bn * K;
    const int NT = K >> 6;

    bf16* L0A = Lsh;
    bf16* L0B = Lsh + AE;
    bf16* L1A = Lsh + AE + BE;
    bf16* L1B = L1A + AE;

    const int urow = t >> 3;                          // row within 64-row unit
    const int csw  = ((t & 7) ^ (urow & 7)) << 3;     // pre-swizzled chunk (elems)
    const int wbase = (t >> 6) << 9;                  // wave LDS base (elems)

    // prologue: A(0),B(0) -> slot0 ; B(1) -> slot1B ; drain ; barrier
    {
#pragma unroll
        for (int u = 0; u < nA; ++u)
            gload16(Ablk + (size_t)(u * 64 + urow) * K + csw, L0A + u * 4096 + wbase);
#pragma unroll
        for (int u = 0; u < nB; ++u)
            gload16(Bblk + (size_t)(u * 64 + urow) * K + csw, L0B + u * 4096 + wbase);
        if (NT > 1) {
#pragma unroll
            for (int u = 0; u < nB; ++u)
                gload16(Bblk + (size_t)(u * 64 + urow) * K + 64 + csw,
                        L1B + u * 4096 + wbase);
        }
        asm volatile("s_waitcnt vmcnt(0)" ::: "memory");
        __builtin_amdgcn_s_barrier();
    }

    f32x4 acc[MF][NF];
#pragma unroll
    for (int i = 0; i < MF; ++i)
#pragma unroll
        for (int j = 0; j < NF; ++j) acc[i][j] = (f32x4){0.f, 0.f, 0.f, 0.f};

    for (int tile = 0; tile < NT; ++tile) {
        bf16* As = (tile & 1) ? L1A : L0A;
        bf16* Bs = (tile & 1) ? L1B : L0B;
        bf16* An = (tile & 1) ? L0A : L1A;
        bf16x8 bfr[NF][2];
#pragma unroll
        for (int q = 0; q < 4; ++q) {
            // ds-read this phase's A sub-tile
            bf16x8 af[MPP][2];
#pragma unroll
            for (int dm = 0; dm < MPP; ++dm)
#pragma unroll
                for (int kk = 0; kk < 2; ++kk) {
                    const int row = wm * (MF * 16) + q * (MPP * 16) + dm * 16 + l15;
                    const int ch  = (kk * 4 + quad) ^ (row & 7);
                    af[dm][kk] = *reinterpret_cast<const bf16x8*>(
                        &As[row * 64 + (ch << 3)]);
                }
            if (q == 0) {
                // all B frags for this tile (held in regs across phases)
#pragma unroll
                for (int n = 0; n < NF; ++n)
#pragma unroll
                    for (int kk = 0; kk < 2; ++kk) {
                        const int row = wn * (NF * 16) + n * 16 + l15;
                        const int ch  = (kk * 4 + quad) ^ (row & 7);
                        bfr[n][kk] = *reinterpret_cast<const bf16x8*>(
                            &Bs[row * 64 + (ch << 3)]);
                    }
            }
            // stage units assigned to this phase (A(t+1) first, then B(t+2))
            if (q < 3) {
#pragma unroll
                for (int u = 0; u < TU; ++u) {
                    if (u / CEIL == q) {
                        if (u < nA) {
                            if (tile + 1 < NT)
                                gload16(Ablk + (size_t)(u * 64 + urow) * K +
                                            (tile + 1) * 64 + csw,
                                        An + u * 4096 + wbase);
                        } else {
                            if (tile + 2 < NT)
                                gload16(Bblk + (size_t)((u - nA) * 64 + urow) * K +
                                            (tile + 2) * 64 + csw,
                                        Bs + (u - nA) * 4096 + wbase);
                        }
                    }
                }
            }
            __builtin_amdgcn_s_barrier();
            asm volatile("s_waitcnt lgkmcnt(0)" ::: "memory");
            __builtin_amdgcn_s_setprio(1);
#pragma unroll
            for (int dm = 0; dm < MPP; ++dm)
#pragma unroll
                for (int n = 0; n < NF; ++n)
#pragma unroll
                    for (int kk = 0; kk < 2; ++kk)
                        acc[q * MPP + dm][n] = __builtin_amdgcn_mfma_f32_16x16x32_bf16(
                            af[dm][kk], bfr[n][kk], acc[q * MPP + dm][n], 0, 0, 0);
            __builtin_amdgcn_s_setprio(0);
            if (q < 3) {
                __builtin_amdgcn_s_barrier();
            } else {
                if (tile < NT - 2) {
                    if constexpr (nB == 3) { asm volatile("s_waitcnt vmcnt(3)" ::: "memory"); }
                    else                   { asm volatile("s_waitcnt vmcnt(4)" ::: "memory"); }
                } else {
                    asm volatile("s_waitcnt vmcnt(0)" ::: "memory");
                }
                __builtin_amdgcn_s_barrier();
            }
        }
    }

    // epilogue: C/D layout col=l15, row=quad*4+r
#pragma unroll
    for (int mf = 0; mf < MF; ++mf) {
        const int row0 = bm + wm * (MF * 16) + mf * 16 + quad * 4;
#pragma unroll
        for (int nf = 0; nf < NF; ++nf) {
            const int col = bn + wn * (NF * 16) + nf * 16 + l15;
#pragma unroll
            for (int r = 0; r < 4; ++r)
                C[(size_t)(row0 + r) * ldc + col] = (OutT)acc[mf][nf][r];
        }
    }
}

// ---------------- RoPE on Q (32 heads) + K (8 heads) in the fused QKV buffer --------
__global__ __launch_bounds__(256) void rope_kernel(bf16* __restrict__ qkv,
                                                   const float* __restrict__ cosT,
                                                   const float* __restrict__ sinT) {
    const int col = blockIdx.x * 256 + threadIdx.x;  // 0 .. 40*64-1
    if (col >= 40 * 64) return;
    const int row  = blockIdx.y;
    const int head = col >> 6, d = col & 63;
    const size_t base = (size_t)row * QKV_N + head * 128 + d;
    const float x1 = (float)qkv[base];
    const float x2 = (float)qkv[base + 64];
    const float c  = cosT[row * 128 + d];
    const float s  = sinT[row * 128 + d];
    qkv[base]      = (bf16)(x1 * c - x2 * s);
    qkv[base + 64] = (bf16)(x2 * c + x1 * s);
}

// ---------------- V transpose: QKV V-region (2048 x 1024) -> Vt (1024 x 2048) -------
__global__ __launch_bounds__(256) void transpose_v(const bf16* __restrict__ qkv,
                                                   bf16* __restrict__ vt) {
    __shared__ bf16 T[64][72];
    const int c0 = blockIdx.x * 64;   // V column tile (0..1023)
    const int s0 = blockIdx.y * 64;   // sequence tile
    const int t  = threadIdx.x;
#pragma unroll
    for (int it = 0; it < 2; ++it) {
        const int sl = (t >> 3) + it * 32;
        const int c8 = (t & 7) * 8;
        bf16x8 v = *reinterpret_cast<const bf16x8*>(
            qkv + (size_t)(s0 + sl) * QKV_N + V_OFF + c0 + c8);
        *reinterpret_cast<bf16x8*>(&T[sl][c8]) = v;
    }
    __syncthreads();
#pragma unroll
    for (int it = 0; it < 2; ++it) {
        const int cl = (t >> 3) + it * 32;
        const int s8 = (t & 7) * 8;
        bf16x8 o;
#pragma unroll
        for (int e = 0; e < 8; ++e) o[e] = T[s8 + e][cl];
        *reinterpret_cast<bf16x8*>(vt + (size_t)(c0 + cl) * S_LEN + s0 + s8) = o;
    }
}

// ---------------- flash attention, causal, GQA group=4 (round-5 proven) ----------
// 512 thr = 8 waves; BQ=128 (16 q-rows/wave), BKV=64, HD=128.
__global__ __launch_bounds__(512) void flash_attn(const bf16* __restrict__ qkv,
                                                  const bf16* __restrict__ vt,
                                                  bf16* __restrict__ ctx) {
    const int blk   = blockIdx.x;
    const int qtile = 15 - (blk >> 5);       // longest blocks dispatched first
    const int h     = blk & 31;
    const int kh    = h >> 2;
    const int q0    = qtile * 128;
    const int t     = threadIdx.x;
    const int wave  = t >> 6, lane = t & 63;
    const int quad  = lane >> 4, l15 = lane & 15;

    __shared__ bf16 Ks[64 * 128];    // 16 KB
    __shared__ bf16 Vs[128 * 64];    // 16 KB
    __shared__ bf16 Ps[8 * 16 * 72]; // 18 KB

    const bf16* Qb  = qkv + h * HD;
    const bf16* Kb  = qkv + K_OFF + kh * HD;
    const bf16* Vth = vt + (size_t)kh * HD * S_LEN;

    const int qrow_a = q0 + wave * 16 + l15;
    bf16x8 qf[4];
#pragma unroll
    for (int kk = 0; kk < 4; ++kk)
        qf[kk] = *reinterpret_cast<const bf16x8*>(
            Qb + (size_t)qrow_a * QKV_N + kk * 32 + quad * 8);

    float m_i[4], l_i[4];
    f32x4 o_acc[8];
#pragma unroll
    for (int r = 0; r < 4; ++r) { m_i[r] = -1e30f; l_i[r] = 0.f; }
#pragma unroll
    for (int dt = 0; dt < 8; ++dt) o_acc[dt] = (f32x4){0.f, 0.f, 0.f, 0.f};

    const int myrow = q0 + wave * 16 + quad * 4;
    bf16* PsW = Ps + wave * (16 * 72);

    for (int kv0 = 0; kv0 < q0 + 128; kv0 += 64) {
        __syncthreads();
#pragma unroll
        for (int it = 0; it < 2; ++it) {
            const int rb = wave * 8 + it * 4;
            const int r  = rb + (lane >> 4);
            const int cg = (lane & 15) ^ (r & 15);
            gload16(Kb + (size_t)(kv0 + r) * QKV_N + cg * 8, Ks + rb * 128);
        }
#pragma unroll
        for (int it = 0; it < 2; ++it) {
            const int db = wave * 16 + it * 8;
            const int d  = db + (lane >> 3);
            const int cg = (lane & 7) ^ (d & 7);
            gload16(Vth + (size_t)d * S_LEN + kv0 + cg * 8, Vs + db * 64);
        }
        __syncthreads();

        float sv[4][4];
        const bool need_mask = (kv0 + 63) > q0;  // block-uniform
#pragma unroll
        for (int j = 0; j < 4; ++j) {
            f32x4 s = (f32x4){0.f, 0.f, 0.f, 0.f};
#pragma unroll
            for (int kk = 0; kk < 4; ++kk) {
                const int cd = kk * 4 + quad;
                bf16x8 kf = *reinterpret_cast<const bf16x8*>(
                    &Ks[(j * 16 + l15) * 128 + ((cd ^ l15) & 15) * 8]);
                s = __builtin_amdgcn_mfma_f32_16x16x32_bf16(qf[kk], kf, s, 0, 0, 0);
            }
            if (need_mask) {
#pragma unroll
                for (int r = 0; r < 4; ++r)
                    sv[j][r] = ((kv0 + j * 16 + l15) <= (myrow + r))
                                   ? s[r] * ATT_SCALE : -1e30f;
            } else {
#pragma unroll
                for (int r = 0; r < 4; ++r) sv[j][r] = s[r] * ATT_SCALE;
            }
        }

        float al[4];
#pragma unroll
        for (int r = 0; r < 4; ++r) {
            float mt = fmaxf(fmaxf(sv[0][r], sv[1][r]), fmaxf(sv[2][r], sv[3][r]));
#pragma unroll
            for (int off = 1; off < 16; off <<= 1) mt = fmaxf(mt, __shfl_xor(mt, off));
            const float mn = fmaxf(m_i[r], mt);
            al[r] = __expf(m_i[r] - mn);
            m_i[r] = mn;
            float rs = 0.f;
#pragma unroll
            for (int j = 0; j < 4; ++j) {
                const float p = __expf(sv[j][r] - mn);
                rs += p;
                PsW[(quad * 4 + r) * 72 + j * 16 + l15] = (bf16)p;
            }
#pragma unroll
            for (int off = 1; off < 16; off <<= 1) rs += __shfl_xor(rs, off);
            l_i[r] = l_i[r] * al[r] + rs;
        }

#pragma unroll
        for (int dt = 0; dt < 8; ++dt) {
            o_acc[dt][0] *= al[0]; o_acc[dt][1] *= al[1];
            o_acc[dt][2] *= al[2]; o_acc[dt][3] *= al[3];
        }

        bf16x8 pa[2];
        pa[0] = *reinterpret_cast<const bf16x8*>(&PsW[l15 * 72 + quad * 8]);
        pa[1] = *reinterpret_cast<const bf16x8*>(&PsW[l15 * 72 + 32 + quad * 8]);
#pragma unroll
        for (int dt = 0; dt < 8; ++dt) {
#pragma unroll
            for (int c = 0; c < 2; ++c) {
                const int ck = c * 4 + quad;
                bf16x8 vb = *reinterpret_cast<const bf16x8*>(
                    &Vs[(dt * 16 + l15) * 64 + ((ck ^ (l15 & 7)) & 7) * 8]);
                o_acc[dt] = __builtin_amdgcn_mfma_f32_16x16x32_bf16(pa[c], vb, o_acc[dt], 0, 0, 0);
            }
        }
    }

#pragma unroll
    for (int dt = 0; dt < 8; ++dt)
#pragma unroll
        for (int r = 0; r < 4; ++r)
            ctx[(size_t)(myrow + r) * DMODEL + h * HD + dt * 16 + l15] =
                (bf16)(o_acc[dt][r] / l_i[r]);
}

// ---------------- launch ----------------
extern "C" void kernel_launch(void* const* d_in, const int* in_sizes, int n_in,
                              void* d_out, int out_size, void* d_ws, size_t ws_size,
                              hipStream_t stream) {
    const float* x    = (const float*)d_in[0];
    const float* cosT = (const float*)d_in[1];
    const float* sinT = (const float*)d_in[2];
    const float* Wq   = (const float*)d_in[3];
    const float* Wk   = (const float*)d_in[4];
    const float* Wv   = (const float*)d_in[5];
    const float* Wo   = (const float*)d_in[6];
    float* out = (float*)d_out;

    // workspace layout (bf16 elems): xb | Wqkv | Wo | QKV | ctx | Vt  (~147 MiB)
    bf16* xb   = (bf16*)d_ws;
    bf16* Wqkv = xb   + (size_t)S_LEN * DMODEL;        // 6144 x 4096
    bf16* Wob  = Wqkv + (size_t)QKV_N * DMODEL;        // 4096 x 4096
    bf16* QKV  = Wob  + (size_t)DMODEL * DMODEL;       // 2048 x 6144
    bf16* ctx  = QKV  + (size_t)S_LEN * QKV_N;         // 2048 x 4096
    bf16* Vt   = ctx  + (size_t)S_LEN * DMODEL;        // 1024 x 2048

    cast_f32_bf16<<<(S_LEN * DMODEL / 4 + 255) / 256, 256, 0, stream>>>(x, xb, S_LEN * DMODEL / 4);
    cast_f32_bf16<<<(DMODEL * DMODEL / 4 + 255) / 256, 256, 0, stream>>>(Wq, Wqkv, DMODEL * DMODEL / 4);
    cast_f32_bf16<<<(1024 * DMODEL / 4 + 255) / 256, 256, 0, stream>>>(
        Wk, Wqkv + (size_t)4096 * DMODEL, 1024 * DMODEL / 4);
    cast_f32_bf16<<<(1024 * DMODEL / 4 + 255) / 256, 256, 0, stream>>>(
        Wv, Wqkv + (size_t)5120 * DMODEL, 1024 * DMODEL / 4);
    cast_f32_bf16<<<(DMODEL * DMODEL / 4 + 255) / 256, 256, 0, stream>>>(Wo, Wob, DMODEL * DMODEL / 4);

    // fused QKV projection: (2048 x 4096) @ (6144 x 4096)^T -> 2048 x 6144 bf16
    gemm256<bf16><<<dim3(QKV_N / 256, S_LEN / 256), 512, 0, stream>>>(
        xb, Wqkv, QKV, S_LEN, QKV_N, DMODEL, QKV_N);

    // RoPE on Q (heads 0..31) and K (heads 32..39 of the packed buffer)
    rope_kernel<<<dim3(10, S_LEN), 256, 0, stream>>>(QKV, cosT, sinT);

    // V transpose for coalesced flash staging
    transpose_v<<<dim3(16, 32), 256, 0, stream>>>(QKV, Vt);

    // flash attention -> ctx bf16 (2048 x 4096); longest-first 1D grid
    flash_attn<<<dim3(16 * 32), 512, 0, stream>>>(QKV, Vt, ctx);

    // output projection: (2048 x 4096) @ (4096 x 4096)^T -> fp32 out
    // 128x256 tiles -> 16 x 16 = 256 blocks (exact CU fill; was 128 blocks)
    gemmT<float, 4, 4><<<dim3(DMODEL / 256, S_LEN / 128), 512, 0, stream>>>(
        ctx, Wob, out, S_LEN, DMODEL, DMODEL, DMODEL);
}

// Round 9
// 498.563 us; speedup vs baseline: 1.1183x; 1.0364x over previous
//
#include <hip/hip_runtime.h>

// GroupedQueryAttention: B=1, S=2048, D_IN=D_OUT=4096, NH=32, NKV=8, HD=128, causal.
// Pipeline: cast->bf16, QKV GEMM (256x192 gemmT, exact fill), RoPE, V-transpose,
// flash attention, out GEMM (128x256 gemmT, exact fill).

typedef __bf16 bf16;
typedef __bf16 bf16x4 __attribute__((ext_vector_type(4)));
typedef __bf16 bf16x8 __attribute__((ext_vector_type(8)));
typedef float  f32x4  __attribute__((ext_vector_type(4)));

#define S_LEN   2048
#define DMODEL  4096
#define QKV_N   6144      // 4096 Q + 1024 K + 1024 V
#define K_OFF   4096
#define V_OFF   5120
#define HD      128
#define ATT_SCALE 0.08838834764831845f  // 1/sqrt(128)

// async global->LDS, 16B per lane; LDS dest is wave-uniform base + lane*16
__device__ __forceinline__ void gload16(const bf16* g, bf16* l) {
    __builtin_amdgcn_global_load_lds(
        (__attribute__((address_space(1))) void*)(g),
        (__attribute__((address_space(3))) void*)(l),
        16, 0, 0);
}

// ---------------- cast fp32 -> bf16, float4 vectorized ----------------
__global__ __launch_bounds__(256) void cast_f32_bf16(const float* __restrict__ in,
                                                     bf16* __restrict__ out, int n4) {
    int i = blockIdx.x * 256 + threadIdx.x;
    if (i >= n4) return;
    float4 v = reinterpret_cast<const float4*>(in)[i];
    bf16x4 o;
    o[0] = (bf16)v.x; o[1] = (bf16)v.y; o[2] = (bf16)v.z; o[3] = (bf16)v.w;
    reinterpret_cast<bf16x4*>(out)[i] = o;
}

// ================= gemmT: BM=MF*32 x BN=NF*64 tile, BK=64, 8-phase counted-vmcnt
// C[M,N] = A[M,K] * B[N,K]^T (row-major, K contiguous).
// 512 threads = 8 waves (2M x 4N); wave computes (MF*16) x (NF*16).
// Instantiations: <bf16,8,3> QKV (256x192 -> 32x8 = 256 blocks, exact CU fill),
//                 <float,4,4> out-proj (128x256 -> 16x16 = 256 blocks).
// Staging in 64-row units (1 gload16/thread/unit): nA=BM/64, nB=BN/64 spread
// over phases 0-2 (A(t+1) first, then B(t+2)). FIFO at tile end:
//   [B(t+1) nB][A(t+1) nA][B(t+2) nB] -> vmcnt(nB) completes the first two,
//   keeps B(t+2) in flight (never drain mid-loop).
// LDS chunk swizzle (both-sides, rule #21): 16B chunk p of row r holds global
// chunk p^(r&7); staged via pre-swizzled global src, read with the same XOR.
template <typename OutT, int MF, int NF>
__global__ __launch_bounds__(512, 2) void gemmT(const bf16* __restrict__ A,
                                                const bf16* __restrict__ B,
                                                OutT* __restrict__ C,
                                                int M, int N, int K, int ldc) {
    constexpr int BM = MF * 32, BN = NF * 64;
    constexpr int nA = BM / 64, nB = BN / 64;
    constexpr int TU = nA + nB;           // stage units per tile
    constexpr int CEIL = (TU + 2) / 3;    // units per phase (phases 0..2)
    constexpr int AE = BM * 64, BE = BN * 64;
    constexpr int MPP = MF / 4;           // M-frags per phase (4 phases)

    __shared__ bf16 Lsh[2 * (AE + BE)];
    const int t    = threadIdx.x;
    const int lane = t & 63;
    const int quad = lane >> 4, l15 = lane & 15;
    const int wave = t >> 6;
    const int wm = wave >> 2, wn = wave & 3;

    // bijective XCD swizzle (m204)
    int bid = blockIdx.y * gridDim.x + blockIdx.x;
    const int nwg = gridDim.x * gridDim.y;
    {
        const int q = nwg >> 3, r = nwg & 7;
        const int x = bid & 7, i = bid >> 3;
        bid = (x < r ? x * (q + 1) : r * (q + 1) + (x - r) * q) + i;
    }
    const int ntm = M / BM;
    const int bm  = (bid % ntm) * BM;   // bn-major: consecutive bids share bn
    const int bn  = (bid / ntm) * BN;

    const bf16* Ablk = A + (size_t)bm * K;
    const bf16* Bblk = B + (size_t)bn * K;
    const int NT = K >> 6;

    bf16* L0A = Lsh;
    bf16* L0B = Lsh + AE;
    bf16* L1A = Lsh + AE + BE;
    bf16* L1B = L1A + AE;

    const int urow = t >> 3;                          // row within 64-row unit
    const int csw  = ((t & 7) ^ (urow & 7)) << 3;     // pre-swizzled chunk (elems)
    const int wbase = (t >> 6) << 9;                  // wave LDS base (elems)

    // prologue: A(0),B(0) -> slot0 ; B(1) -> slot1B ; drain ; barrier
    {
#pragma unroll
        for (int u = 0; u < nA; ++u)
            gload16(Ablk + (size_t)(u * 64 + urow) * K + csw, L0A + u * 4096 + wbase);
#pragma unroll
        for (int u = 0; u < nB; ++u)
            gload16(Bblk + (size_t)(u * 64 + urow) * K + csw, L0B + u * 4096 + wbase);
        if (NT > 1) {
#pragma unroll
            for (int u = 0; u < nB; ++u)
                gload16(Bblk + (size_t)(u * 64 + urow) * K + 64 + csw,
                        L1B + u * 4096 + wbase);
        }
        asm volatile("s_waitcnt vmcnt(0)" ::: "memory");
        __builtin_amdgcn_s_barrier();
    }

    f32x4 acc[MF][NF];
#pragma unroll
    for (int i = 0; i < MF; ++i)
#pragma unroll
        for (int j = 0; j < NF; ++j) acc[i][j] = (f32x4){0.f, 0.f, 0.f, 0.f};

    for (int tile = 0; tile < NT; ++tile) {
        bf16* As = (tile & 1) ? L1A : L0A;
        bf16* Bs = (tile & 1) ? L1B : L0B;
        bf16* An = (tile & 1) ? L0A : L1A;
        bf16x8 bfr[NF][2];
#pragma unroll
        for (int q = 0; q < 4; ++q) {
            // ds-read this phase's A sub-tile
            bf16x8 af[MPP][2];
#pragma unroll
            for (int dm = 0; dm < MPP; ++dm)
#pragma unroll
                for (int kk = 0; kk < 2; ++kk) {
                    const int row = wm * (MF * 16) + q * (MPP * 16) + dm * 16 + l15;
                    const int ch  = (kk * 4 + quad) ^ (row & 7);
                    af[dm][kk] = *reinterpret_cast<const bf16x8*>(
                        &As[row * 64 + (ch << 3)]);
                }
            if (q == 0) {
                // all B frags for this tile (held in regs across phases)
#pragma unroll
                for (int n = 0; n < NF; ++n)
#pragma unroll
                    for (int kk = 0; kk < 2; ++kk) {
                        const int row = wn * (NF * 16) + n * 16 + l15;
                        const int ch  = (kk * 4 + quad) ^ (row & 7);
                        bfr[n][kk] = *reinterpret_cast<const bf16x8*>(
                            &Bs[row * 64 + (ch << 3)]);
                    }
            }
            // stage units assigned to this phase (A(t+1) first, then B(t+2))
            if (q < 3) {
#pragma unroll
                for (int u = 0; u < TU; ++u) {
                    if (u / CEIL == q) {
                        if (u < nA) {
                            if (tile + 1 < NT)
                                gload16(Ablk + (size_t)(u * 64 + urow) * K +
                                            (tile + 1) * 64 + csw,
                                        An + u * 4096 + wbase);
                        } else {
                            if (tile + 2 < NT)
                                gload16(Bblk + (size_t)((u - nA) * 64 + urow) * K +
                                            (tile + 2) * 64 + csw,
                                        Bs + (u - nA) * 4096 + wbase);
                        }
                    }
                }
            }
            __builtin_amdgcn_s_barrier();
            asm volatile("s_waitcnt lgkmcnt(0)" ::: "memory");
            __builtin_amdgcn_s_setprio(1);
#pragma unroll
            for (int dm = 0; dm < MPP; ++dm)
#pragma unroll
                for (int n = 0; n < NF; ++n)
#pragma unroll
                    for (int kk = 0; kk < 2; ++kk)
                        acc[q * MPP + dm][n] = __builtin_amdgcn_mfma_f32_16x16x32_bf16(
                            af[dm][kk], bfr[n][kk], acc[q * MPP + dm][n], 0, 0, 0);
            __builtin_amdgcn_s_setprio(0);
            if (q < 3) {
                __builtin_amdgcn_s_barrier();
            } else {
                if (tile < NT - 2) {
                    if constexpr (nB == 3) { asm volatile("s_waitcnt vmcnt(3)" ::: "memory"); }
                    else                   { asm volatile("s_waitcnt vmcnt(4)" ::: "memory"); }
                } else {
                    asm volatile("s_waitcnt vmcnt(0)" ::: "memory");
                }
                __builtin_amdgcn_s_barrier();
            }
        }
    }

    // epilogue: C/D layout col=l15, row=quad*4+r
#pragma unroll
    for (int mf = 0; mf < MF; ++mf) {
        const int row0 = bm + wm * (MF * 16) + mf * 16 + quad * 4;
#pragma unroll
        for (int nf = 0; nf < NF; ++nf) {
            const int col = bn + wn * (NF * 16) + nf * 16 + l15;
#pragma unroll
            for (int r = 0; r < 4; ++r)
                C[(size_t)(row0 + r) * ldc + col] = (OutT)acc[mf][nf][r];
        }
    }
}

// ---------------- RoPE on Q (32 heads) + K (8 heads) in the fused QKV buffer --------
__global__ __launch_bounds__(256) void rope_kernel(bf16* __restrict__ qkv,
                                                   const float* __restrict__ cosT,
                                                   const float* __restrict__ sinT) {
    const int col = blockIdx.x * 256 + threadIdx.x;  // 0 .. 40*64-1
    if (col >= 40 * 64) return;
    const int row  = blockIdx.y;
    const int head = col >> 6, d = col & 63;
    const size_t base = (size_t)row * QKV_N + head * 128 + d;
    const float x1 = (float)qkv[base];
    const float x2 = (float)qkv[base + 64];
    const float c  = cosT[row * 128 + d];
    const float s  = sinT[row * 128 + d];
    qkv[base]      = (bf16)(x1 * c - x2 * s);
    qkv[base + 64] = (bf16)(x2 * c + x1 * s);
}

// ---------------- V transpose: QKV V-region (2048 x 1024) -> Vt (1024 x 2048) -------
__global__ __launch_bounds__(256) void transpose_v(const bf16* __restrict__ qkv,
                                                   bf16* __restrict__ vt) {
    __shared__ bf16 T[64][72];
    const int c0 = blockIdx.x * 64;   // V column tile (0..1023)
    const int s0 = blockIdx.y * 64;   // sequence tile
    const int t  = threadIdx.x;
#pragma unroll
    for (int it = 0; it < 2; ++it) {
        const int sl = (t >> 3) + it * 32;
        const int c8 = (t & 7) * 8;
        bf16x8 v = *reinterpret_cast<const bf16x8*>(
            qkv + (size_t)(s0 + sl) * QKV_N + V_OFF + c0 + c8);
        *reinterpret_cast<bf16x8*>(&T[sl][c8]) = v;
    }
    __syncthreads();
#pragma unroll
    for (int it = 0; it < 2; ++it) {
        const int cl = (t >> 3) + it * 32;
        const int s8 = (t & 7) * 8;
        bf16x8 o;
#pragma unroll
        for (int e = 0; e < 8; ++e) o[e] = T[s8 + e][cl];
        *reinterpret_cast<bf16x8*>(vt + (size_t)(c0 + cl) * S_LEN + s0 + s8) = o;
    }
}

// ---------------- flash attention, causal, GQA group=4 (round-5 proven) ----------
// 512 thr = 8 waves; BQ=128 (16 q-rows/wave), BKV=64, HD=128.
__global__ __launch_bounds__(512) void flash_attn(const bf16* __restrict__ qkv,
                                                  const bf16* __restrict__ vt,
                                                  bf16* __restrict__ ctx) {
    const int blk   = blockIdx.x;
    const int qtile = 15 - (blk >> 5);       // longest blocks dispatched first
    const int h     = blk & 31;
    const int kh    = h >> 2;
    const int q0    = qtile * 128;
    const int t     = threadIdx.x;
    const int wave  = t >> 6, lane = t & 63;
    const int quad  = lane >> 4, l15 = lane & 15;

    __shared__ bf16 Ks[64 * 128];    // 16 KB
    __shared__ bf16 Vs[128 * 64];    // 16 KB
    __shared__ bf16 Ps[8 * 16 * 72]; // 18 KB

    const bf16* Qb  = qkv + h * HD;
    const bf16* Kb  = qkv + K_OFF + kh * HD;
    const bf16* Vth = vt + (size_t)kh * HD * S_LEN;

    const int qrow_a = q0 + wave * 16 + l15;
    bf16x8 qf[4];
#pragma unroll
    for (int kk = 0; kk < 4; ++kk)
        qf[kk] = *reinterpret_cast<const bf16x8*>(
            Qb + (size_t)qrow_a * QKV_N + kk * 32 + quad * 8);

    float m_i[4], l_i[4];
    f32x4 o_acc[8];
#pragma unroll
    for (int r = 0; r < 4; ++r) { m_i[r] = -1e30f; l_i[r] = 0.f; }
#pragma unroll
    for (int dt = 0; dt < 8; ++dt) o_acc[dt] = (f32x4){0.f, 0.f, 0.f, 0.f};

    const int myrow = q0 + wave * 16 + quad * 4;
    bf16* PsW = Ps + wave * (16 * 72);

    for (int kv0 = 0; kv0 < q0 + 128; kv0 += 64) {
        __syncthreads();
#pragma unroll
        for (int it = 0; it < 2; ++it) {
            const int rb = wave * 8 + it * 4;
            const int r  = rb + (lane >> 4);
            const int cg = (lane & 15) ^ (r & 15);
            gload16(Kb + (size_t)(kv0 + r) * QKV_N + cg * 8, Ks + rb * 128);
        }
#pragma unroll
        for (int it = 0; it < 2; ++it) {
            const int db = wave * 16 + it * 8;
            const int d  = db + (lane >> 3);
            const int cg = (lane & 7) ^ (d & 7);
            gload16(Vth + (size_t)d * S_LEN + kv0 + cg * 8, Vs + db * 64);
        }
        __syncthreads();

        float sv[4][4];
        const bool need_mask = (kv0 + 63) > q0;  // block-uniform
#pragma unroll
        for (int j = 0; j < 4; ++j) {
            f32x4 s = (f32x4){0.f, 0.f, 0.f, 0.f};
#pragma unroll
            for (int kk = 0; kk < 4; ++kk) {
                const int cd = kk * 4 + quad;
                bf16x8 kf = *reinterpret_cast<const bf16x8*>(
                    &Ks[(j * 16 + l15) * 128 + ((cd ^ l15) & 15) * 8]);
                s = __builtin_amdgcn_mfma_f32_16x16x32_bf16(qf[kk], kf, s, 0, 0, 0);
            }
            if (need_mask) {
#pragma unroll
                for (int r = 0; r < 4; ++r)
                    sv[j][r] = ((kv0 + j * 16 + l15) <= (myrow + r))
                                   ? s[r] * ATT_SCALE : -1e30f;
            } else {
#pragma unroll
                for (int r = 0; r < 4; ++r) sv[j][r] = s[r] * ATT_SCALE;
            }
        }

        float al[4];
#pragma unroll
        for (int r = 0; r < 4; ++r) {
            float mt = fmaxf(fmaxf(sv[0][r], sv[1][r]), fmaxf(sv[2][r], sv[3][r]));
#pragma unroll
            for (int off = 1; off < 16; off <<= 1) mt = fmaxf(mt, __shfl_xor(mt, off));
            const float mn = fmaxf(m_i[r], mt);
            al[r] = __expf(m_i[r] - mn);
            m_i[r] = mn;
            float rs = 0.f;
#pragma unroll
            for (int j = 0; j < 4; ++j) {
                const float p = __expf(sv[j][r] - mn);
                rs += p;
                PsW[(quad * 4 + r) * 72 + j * 16 + l15] = (bf16)p;
            }
#pragma unroll
            for (int off = 1; off < 16; off <<= 1) rs += __shfl_xor(rs, off);
            l_i[r] = l_i[r] * al[r] + rs;
        }

#pragma unroll
        for (int dt = 0; dt < 8; ++dt) {
            o_acc[dt][0] *= al[0]; o_acc[dt][1] *= al[1];
            o_acc[dt][2] *= al[2]; o_acc[dt][3] *= al[3];
        }

        bf16x8 pa[2];
        pa[0] = *reinterpret_cast<const bf16x8*>(&PsW[l15 * 72 + quad * 8]);
        pa[1] = *reinterpret_cast<const bf16x8*>(&PsW[l15 * 72 + 32 + quad * 8]);
#pragma unroll
        for (int dt = 0; dt < 8; ++dt) {
#pragma unroll
            for (int c = 0; c < 2; ++c) {
                const int ck = c * 4 + quad;
                bf16x8 vb = *reinterpret_cast<const bf16x8*>(
                    &Vs[(dt * 16 + l15) * 64 + ((ck ^ (l15 & 7)) & 7) * 8]);
                o_acc[dt] = __builtin_amdgcn_mfma_f32_16x16x32_bf16(pa[c], vb, o_acc[dt], 0, 0, 0);
            }
        }
    }

#pragma unroll
    for (int dt = 0; dt < 8; ++dt)
#pragma unroll
        for (int r = 0; r < 4; ++r)
            ctx[(size_t)(myrow + r) * DMODEL + h * HD + dt * 16 + l15] =
                (bf16)(o_acc[dt][r] / l_i[r]);
}

// ---------------- launch ----------------
extern "C" void kernel_launch(void* const* d_in, const int* in_sizes, int n_in,
                              void* d_out, int out_size, void* d_ws, size_t ws_size,
                              hipStream_t stream) {
    const float* x    = (const float*)d_in[0];
    const float* cosT = (const float*)d_in[1];
    const float* sinT = (const float*)d_in[2];
    const float* Wq   = (const float*)d_in[3];
    const float* Wk   = (const float*)d_in[4];
    const float* Wv   = (const float*)d_in[5];
    const float* Wo   = (const float*)d_in[6];
    float* out = (float*)d_out;

    // workspace layout (bf16 elems): xb | Wqkv | Wo | QKV | ctx | Vt  (~147 MiB)
    bf16* xb   = (bf16*)d_ws;
    bf16* Wqkv = xb   + (size_t)S_LEN * DMODEL;        // 6144 x 4096
    bf16* Wob  = Wqkv + (size_t)QKV_N * DMODEL;        // 4096 x 4096
    bf16* QKV  = Wob  + (size_t)DMODEL * DMODEL;       // 2048 x 6144
    bf16* ctx  = QKV  + (size_t)S_LEN * QKV_N;         // 2048 x 4096
    bf16* Vt   = ctx  + (size_t)S_LEN * DMODEL;        // 1024 x 2048

    cast_f32_bf16<<<(S_LEN * DMODEL / 4 + 255) / 256, 256, 0, stream>>>(x, xb, S_LEN * DMODEL / 4);
    cast_f32_bf16<<<(DMODEL * DMODEL / 4 + 255) / 256, 256, 0, stream>>>(Wq, Wqkv, DMODEL * DMODEL / 4);
    cast_f32_bf16<<<(1024 * DMODEL / 4 + 255) / 256, 256, 0, stream>>>(
        Wk, Wqkv + (size_t)4096 * DMODEL, 1024 * DMODEL / 4);
    cast_f32_bf16<<<(1024 * DMODEL / 4 + 255) / 256, 256, 0, stream>>>(
        Wv, Wqkv + (size_t)5120 * DMODEL, 1024 * DMODEL / 4);
    cast_f32_bf16<<<(DMODEL * DMODEL / 4 + 255) / 256, 256, 0, stream>>>(Wo, Wob, DMODEL * DMODEL / 4);

    // fused QKV projection: (2048 x 4096) @ (6144 x 4096)^T -> 2048 x 6144 bf16
    // 256x192 tiles -> 32 x 8 = 256 blocks (exact CU fill; was 192 blocks = 75%)
    gemmT<bf16, 8, 3><<<dim3(QKV_N / 192, S_LEN / 256), 512, 0, stream>>>(
        xb, Wqkv, QKV, S_LEN, QKV_N, DMODEL, QKV_N);

    // RoPE on Q (heads 0..31) and K (heads 32..39 of the packed buffer)
    rope_kernel<<<dim3(10, S_LEN), 256, 0, stream>>>(QKV, cosT, sinT);

    // V transpose for coalesced flash staging
    transpose_v<<<dim3(16, 32), 256, 0, stream>>>(QKV, Vt);

    // flash attention -> ctx bf16 (2048 x 4096); longest-first 1D grid
    flash_attn<<<dim3(16 * 32), 512, 0, stream>>>(QKV, Vt, ctx);

    // output projection: (2048 x 4096) @ (4096 x 4096)^T -> fp32 out
    // 128x256 tiles -> 16 x 16 = 256 blocks (exact CU fill)
    gemmT<float, 4, 4><<<dim3(DMODEL / 256, S_LEN / 128), 512, 0, stream>>>(
        ctx, Wob, out, S_LEN, DMODEL, DMODEL, DMODEL);
}